// Round 5
// baseline (632.927 us; speedup 1.0000x reference)
//
#include <hip/hip_runtime.h>
#include <math.h>

#define D 128
#define BSHIFT 9              // bucket = 512 nodes
#define BCAP 12288            // LDS staging capacity (edges) per bucket

typedef __attribute__((ext_vector_type(8))) _Float16 half8;
typedef __attribute__((ext_vector_type(4))) float floatx4;
typedef __attribute__((ext_vector_type(4))) unsigned uintx4;

// ---------------- threefry2x32 (JAX-compatible, 20 rounds) ----------------
__host__ __device__ __forceinline__ unsigned rotl32(unsigned v, int r) {
  return (v << r) | (v >> (32 - r));
}

__host__ __device__ __forceinline__ void threefry2x32(unsigned k0, unsigned k1,
                                                      unsigned x0, unsigned x1,
                                                      unsigned &o0, unsigned &o1) {
  unsigned ks2 = k0 ^ k1 ^ 0x1BD11BDAu;
  unsigned v0 = x0 + k0;
  unsigned v1 = x1 + k1;
  v0 += v1; v1 = rotl32(v1, 13); v1 ^= v0;
  v0 += v1; v1 = rotl32(v1, 15); v1 ^= v0;
  v0 += v1; v1 = rotl32(v1, 26); v1 ^= v0;
  v0 += v1; v1 = rotl32(v1, 6);  v1 ^= v0;
  v0 += k1; v1 += ks2 + 1u;
  v0 += v1; v1 = rotl32(v1, 17); v1 ^= v0;
  v0 += v1; v1 = rotl32(v1, 29); v1 ^= v0;
  v0 += v1; v1 = rotl32(v1, 16); v1 ^= v0;
  v0 += v1; v1 = rotl32(v1, 24); v1 ^= v0;
  v0 += ks2; v1 += k0 + 2u;
  v0 += v1; v1 = rotl32(v1, 13); v1 ^= v0;
  v0 += v1; v1 = rotl32(v1, 15); v1 ^= v0;
  v0 += v1; v1 = rotl32(v1, 26); v1 ^= v0;
  v0 += v1; v1 = rotl32(v1, 6);  v1 ^= v0;
  v0 += k0; v1 += k1 + 3u;
  v0 += v1; v1 = rotl32(v1, 17); v1 ^= v0;
  v0 += v1; v1 = rotl32(v1, 29); v1 ^= v0;
  v0 += v1; v1 = rotl32(v1, 16); v1 ^= v0;
  v0 += v1; v1 = rotl32(v1, 24); v1 ^= v0;
  v0 += k1; v1 += ks2 + 4u;
  v0 += v1; v1 = rotl32(v1, 13); v1 ^= v0;
  v0 += v1; v1 = rotl32(v1, 15); v1 ^= v0;
  v0 += v1; v1 = rotl32(v1, 26); v1 ^= v0;
  v0 += v1; v1 = rotl32(v1, 6);  v1 ^= v0;
  v0 += ks2; v1 += k0 + 5u;
  o0 = v0; o1 = v1;
}

// float -> fp16 bits (RNE via v_cvt_f16_f32)
__device__ __forceinline__ unsigned short f2h(float f) {
  _Float16 h = (_Float16)f;
  return *(unsigned short*)&h;
}

// packed fp16 max (VOP3P, 1 instr for 2 elements)
__device__ __forceinline__ unsigned pkmax(unsigned a, unsigned b) {
  unsigned r;
  asm("v_pk_max_f16 %0, %1, %2" : "=v"(r) : "v"(a), "v"(b));
  return r;
}

// ================= CSR build (bucket-local, no global per-node atomics) ====

__global__ __launch_bounds__(256) void bucket_count_kernel(
    const int* __restrict__ dst, int* __restrict__ bucketTotal, int nEdges) {
  __shared__ int lc[256];
  int t = threadIdx.x;
  lc[t] = 0;
  __syncthreads();
  int e0 = blockIdx.x * 4096;
  for (int i = t; i < 4096; i += 256) {
    int e = e0 + i;
    if (e < nEdges) atomicAdd(&lc[dst[e] >> BSHIFT], 1);
  }
  __syncthreads();
  int c = lc[t];
  if (c > 0) atomicAdd(&bucketTotal[t], c);
}

__global__ __launch_bounds__(256) void scan_buckets_kernel(
    const int* __restrict__ bucketTotal, int* __restrict__ buckOff,
    int* __restrict__ bucketCursor, int nBuck) {
  __shared__ int s[256];
  int t = threadIdx.x;
  int v = (t < nBuck) ? bucketTotal[t] : 0;
  s[t] = v;
  __syncthreads();
  for (int off = 1; off < 256; off <<= 1) {
    int u = (t >= off) ? s[t - off] : 0;
    __syncthreads();
    s[t] += u;
    __syncthreads();
  }
  int excl = s[t] - v;
  if (t < nBuck) {
    buckOff[t] = excl;
    bucketCursor[t] = excl;
  } else if (t == nBuck) {
    buckOff[t] = s[255];  // total edge count
  }
}

// pairs entry packed: (src << 9) | (dst & 511)  — src < 2^17, fits 26 bits.
__global__ __launch_bounds__(256) void bucket_scatter_kernel(
    const int* __restrict__ src, const int* __restrict__ dst,
    int* __restrict__ bucketCursor, unsigned* __restrict__ pairs,
    int nEdges, int nBuck) {
  __shared__ int lcount[256];
  __shared__ int lbase[256];
  __shared__ int loff[256];
  int t = threadIdx.x;
  lcount[t] = 0; loff[t] = 0;
  __syncthreads();
  int e0 = blockIdx.x * 4096;
  for (int i = t; i < 4096; i += 256) {
    int e = e0 + i;
    if (e < nEdges) atomicAdd(&lcount[dst[e] >> BSHIFT], 1);
  }
  __syncthreads();
  if (t < nBuck) {
    int c = lcount[t];
    if (c > 0) lbase[t] = atomicAdd(&bucketCursor[t], c);
  }
  __syncthreads();
  for (int i = t; i < 4096; i += 256) {
    int e = e0 + i;
    if (e < nEdges) {
      int d = dst[e];
      int b = d >> BSHIFT;
      int lp = atomicAdd(&loff[b], 1);
      pairs[lbase[b] + lp] = ((unsigned)src[e] << BSHIFT) | ((unsigned)d & 511u);
    }
  }
}

// One block per bucket: count degrees in LDS, scan in LDS, emit rowStart,
// then single-writer place into csrSrc.
__global__ __launch_bounds__(256) void local_fill_kernel(
    const unsigned* __restrict__ pairs, const int* __restrict__ buckOff,
    int* __restrict__ rowStart, int* __restrict__ csrSrc,
    int nNodes, int nBuck) {
  __shared__ int sData[BCAP];           // 48 KB
  __shared__ int lcnt[1 << BSHIFT];     // 2 KB: counts, then running cursors
  __shared__ int sSum[256];             // 1 KB scan temp
  int b = blockIdx.x;
  int node0 = b << BSHIFT;
  int base = buckOff[b];
  int end = buckOff[b + 1];
  int cnt = end - base;
  int t = threadIdx.x;

  lcnt[t] = 0;
  lcnt[t + 256] = 0;
  __syncthreads();

  for (int i = base + t; i < end; i += 256)
    atomicAdd(&lcnt[pairs[i] & 511u], 1);
  __syncthreads();

  int c0 = lcnt[2 * t];
  int c1 = lcnt[2 * t + 1];
  int local = c0 + c1;
  sSum[t] = local;
  __syncthreads();
  for (int off = 1; off < 256; off <<= 1) {
    int v = (t >= off) ? sSum[t - off] : 0;
    __syncthreads();
    sSum[t] += v;
    __syncthreads();
  }
  int excl = sSum[t] - local;
  __syncthreads();
  lcnt[2 * t] = excl;
  lcnt[2 * t + 1] = excl + c0;
  int n0 = node0 + 2 * t;
  int n1 = n0 + 1;
  if (n0 < nNodes) rowStart[n0] = base + excl;
  if (n1 < nNodes) rowStart[n1] = base + excl + c0;
  if (b == nBuck - 1 && t == 255) rowStart[nNodes] = end;
  __syncthreads();

  if (cnt <= BCAP) {
    for (int i = base + t; i < end; i += 256) {
      unsigned p = pairs[i];
      int lp = atomicAdd(&lcnt[p & 511u], 1);
      sData[lp] = (int)(p >> BSHIFT);
    }
    __syncthreads();
    for (int i = t; i < cnt; i += 256)
      csrSrc[base + i] = sData[i];
  } else {
    for (int i = base + t; i < end; i += 256) {
      unsigned p = pairs[i];
      int lp = atomicAdd(&lcnt[p & 511u], 1);
      csrSrc[base + lp] = (int)(p >> BSHIFT);
    }
  }
}

// ========== prep: fp32 node-major -> fp16 SLICE-MAJOR [8][N][32B] ==========
__global__ __launch_bounds__(256) void convert_feat_slice_kernel(
    const float* __restrict__ f, unsigned short* __restrict__ o, int nN) {
  int s = blockIdx.y;
  int rem = blockIdx.x * 256 + threadIdx.x;   // [0, nN*2)
  if (rem >= nN * 2) return;
  int n = rem >> 1, h = rem & 1;
  const float* src = f + (size_t)n * D + s * 16 + h * 8;
  float4 v0 = *((const float4*)src);
  float4 v1 = *((const float4*)(src + 4));
  uint4 out;
  out.x = (unsigned)f2h(v0.x) | ((unsigned)f2h(v0.y) << 16);
  out.y = (unsigned)f2h(v0.z) | ((unsigned)f2h(v0.w) << 16);
  out.z = (unsigned)f2h(v1.x) | ((unsigned)f2h(v1.y) << 16);
  out.w = (unsigned)f2h(v1.z) | ((unsigned)f2h(v1.w) << 16);
  ((uint4*)o)[((size_t)s * nN + n) * 2 + h] = out;
}

// Wt[l][n][k] fp16, k<128 from Wl[k][n], k>=128 from Wr[k-128][n]
__global__ __launch_bounds__(256) void pack_weights_kernel(
    const float* __restrict__ Wl0, const float* __restrict__ Wr0,
    const float* __restrict__ Wl1, const float* __restrict__ Wr1,
    const float* __restrict__ Wl2, const float* __restrict__ Wr2,
    unsigned short* __restrict__ Wt) {
  int t = blockIdx.x * 256 + threadIdx.x;
  if (t >= 3 * 128 * 256) return;
  int l = t >> 15;
  int rem = t & 32767;
  int n = rem >> 8;
  int k = rem & 255;
  const float* Wl = (l == 0) ? Wl0 : (l == 1) ? Wl1 : Wl2;
  const float* Wr = (l == 0) ? Wr0 : (l == 1) ? Wr1 : Wr2;
  float v = (k < 128) ? Wl[k * D + n] : Wr[(k - 128) * D + n];
  Wt[t] = f2h(v);
}

// ============== gather segment-max, slice-major + XCD affinity ==============
// slice = blockIdx % 8 -> under round-robin block->XCD mapping, XCD s only
// touches slice region s (3.2 MB), which fits its 4 MB L2 -> L2-resident.
// Lane layout: 4 nodes/wave (lane>>4), 8 edge slots ((lane&15)>>1), 2 half-
// granules (lane&1). 16 nodes per block.
__global__ __launch_bounds__(256) void gather_max_slice_kernel(
    const uint4* __restrict__ xs, const int* __restrict__ rowStart,
    const int* __restrict__ csrSrc, uint4* __restrict__ aggs, int nN) {
  int b = blockIdx.x;
  int s = b & 7;
  int nb = b >> 3;
  int tid = threadIdx.x;
  int wv = tid >> 6, lane = tid & 63;
  int nq = lane >> 4;            // node quarter [0,4)
  int slot = (lane & 15) >> 1;   // edge slot [0,8)
  int h = lane & 1;              // 16B half of the 32B granule
  int n = nb * 16 + wv * 4 + nq;
  if (n >= nN) return;           // quarter-uniform (shuffles stay in-quarter)
  int e0 = rowStart[n], e1 = rowStart[n + 1];
  size_t sbase = (size_t)s * nN;
  unsigned m0 = 0xFC00FC00u, m1 = 0xFC00FC00u,  // packed fp16 -inf
           m2 = 0xFC00FC00u, m3 = 0xFC00FC00u;
  for (int e = e0 + slot; e < e1; e += 8) {
    int idx = __builtin_nontemporal_load(&csrSrc[e]);  // stream, no L2 pollute
    uint4 v = xs[(sbase + (unsigned)idx) * 2 + h];     // L2-resident granule
    m0 = pkmax(m0, v.x); m1 = pkmax(m1, v.y);
    m2 = pkmax(m2, v.z); m3 = pkmax(m3, v.w);
  }
  // reduce over the 8 edge slots (xor 2,4,8 within the 16-lane quarter)
  m0 = pkmax(m0, (unsigned)__shfl_xor((int)m0, 2, 64));
  m1 = pkmax(m1, (unsigned)__shfl_xor((int)m1, 2, 64));
  m2 = pkmax(m2, (unsigned)__shfl_xor((int)m2, 2, 64));
  m3 = pkmax(m3, (unsigned)__shfl_xor((int)m3, 2, 64));
  m0 = pkmax(m0, (unsigned)__shfl_xor((int)m0, 4, 64));
  m1 = pkmax(m1, (unsigned)__shfl_xor((int)m1, 4, 64));
  m2 = pkmax(m2, (unsigned)__shfl_xor((int)m2, 4, 64));
  m3 = pkmax(m3, (unsigned)__shfl_xor((int)m3, 4, 64));
  m0 = pkmax(m0, (unsigned)__shfl_xor((int)m0, 8, 64));
  m1 = pkmax(m1, (unsigned)__shfl_xor((int)m1, 8, 64));
  m2 = pkmax(m2, (unsigned)__shfl_xor((int)m2, 8, 64));
  m3 = pkmax(m3, (unsigned)__shfl_xor((int)m3, 8, 64));
  if ((lane & 15) < 2) {
    uintx4 r = {0u, 0u, 0u, 0u};   // isolated node -> +0.0
    if (e0 != e1) { r.x = m0; r.y = m1; r.z = m2; r.w = m3; }
    __builtin_nontemporal_store(r, (uintx4*)&aggs[(sbase + n) * 2 + h]);
  }
}

// ====== MFMA layer: 64-row tile, slice-major in/out, coalesced stores ======
#define PA 280
#define TROWS 64

__global__ __launch_bounds__(256, 2) void fused_mfma_kernel(
    const unsigned short* __restrict__ agghf, unsigned short* __restrict__ xhf,
    const unsigned short* __restrict__ Wt, const float* __restrict__ bias,
    float* __restrict__ outF, int nRows, int mode, unsigned kk0, unsigned kk1) {
  __shared__ unsigned short sA[TROWS * PA];   // 35.8 KB

  const int tid = threadIdx.x;
  const int row0 = blockIdx.x * TROWS;
  const int wv = tid >> 6, lane = tid & 63;
  const int quad = lane >> 4, m16 = lane & 15;
  const int nbase = wv * 32;
  const int nN = nRows;
  const uint4* ag4 = (const uint4*)agghf;
  const uint4* xf4 = (const uint4*)xhf;

  // ---- stage A: 64 rows x 256 k from slice-major agg (k<128) + self ----
#pragma unroll
  for (int i = 0; i < 8; ++i) {
    int idx = i * 256 + tid;        // [0,2048)
    int part = idx >> 10;           // 0 = agg, 1 = self
    int rem = idx & 1023;
    int s = rem >> 7;
    int r = (rem >> 1) & 63;
    int h = rem & 1;
    uint4 v = make_uint4(0, 0, 0, 0);
    if (row0 + r < nRows) {
      const uint4* srcp = part ? xf4 : ag4;
      v = srcp[((size_t)s * nN + row0 + r) * 2 + h];
    }
    *((uint4*)(sA + r * PA + part * 128 + s * 16 + h * 8)) = v;
  }

  // ---- B fragments (L2-resident weights) ----
  half8 bfr[2][4][2];
#pragma unroll
  for (int kc = 0; kc < 2; ++kc)
#pragma unroll
    for (int ks = 0; ks < 4; ++ks)
#pragma unroll
      for (int j = 0; j < 2; ++j)
        bfr[kc][ks][j] = *((const half8*)(
            Wt + (size_t)(nbase + j * 16 + m16) * 256 + kc * 128 + ks * 32 + quad * 8));

  floatx4 acc[4][2];
#pragma unroll
  for (int i = 0; i < 4; ++i)
#pragma unroll
    for (int j = 0; j < 2; ++j) acc[i][j] = (floatx4)(0.0f);

  __syncthreads();

#pragma unroll
  for (int kc = 0; kc < 2; ++kc)
#pragma unroll
    for (int ks = 0; ks < 4; ++ks) {
      int kA = kc * 128 + ks * 32 + quad * 8;
#pragma unroll
      for (int i = 0; i < 4; ++i) {
        half8 a = *((const half8*)(sA + (m16 + 16 * i) * PA + kA));
        acc[i][0] = __builtin_amdgcn_mfma_f32_16x16x32_f16(a, bfr[kc][ks][0], acc[i][0], 0, 0, 0);
        acc[i][1] = __builtin_amdgcn_mfma_f32_16x16x32_f16(a, bfr[kc][ks][1], acc[i][1], 0, 0, 0);
      }
    }

  if (mode < 2) {
    // epilogue: ELU + dropout, stage fp16 tile in LDS, slice-major store
    __syncthreads();   // all MFMA reads of sA done before overwrite
#pragma unroll
    for (int j = 0; j < 2; ++j) {
      int col = nbase + j * 16 + m16;
      float bc = bias[col];
#pragma unroll
      for (int i = 0; i < 4; ++i) {
#pragma unroll
        for (int reg = 0; reg < 4; ++reg) {
          int r = i * 16 + quad * 4 + reg;
          if (row0 + r >= nRows) continue;
          float v = acc[i][j][reg] + bc;
          v = (v > 0.0f) ? v : (__expf(v) - 1.0f);   // ELU via hw exp
          unsigned jj = (unsigned)(row0 + r) * D + col;
          unsigned y0, y1;
          threefry2x32(kk0, kk1, 0u, jj, y0, y1);
          float u = __uint_as_float((((y0 ^ y1) >> 9)) | 0x3F800000u) - 1.0f;
          v = (u < 0.8f) ? v * 1.25f : 0.0f;
          sA[r * PA + col] = f2h(v);
        }
      }
    }
    __syncthreads();
    uint4* out4 = (uint4*)xhf;
#pragma unroll
    for (int i = 0; i < 4; ++i) {
      int idx = i * 256 + tid;      // [0,1024)
      int s = idx >> 7;
      int r = (idx >> 1) & 63;
      int h = idx & 1;
      if (row0 + r < nRows)
        out4[((size_t)s * nN + row0 + r) * 2 + h] =
            *((const uint4*)(sA + r * PA + s * 16 + h * 8));
    }
  } else {
    // final layer: fp32 out (node-major), 64 B-contiguous stores per quad
#pragma unroll
    for (int j = 0; j < 2; ++j) {
      int col = nbase + j * 16 + m16;
      float bc = bias[col];
#pragma unroll
      for (int i = 0; i < 4; ++i) {
#pragma unroll
        for (int reg = 0; reg < 4; ++reg) {
          int r = row0 + i * 16 + quad * 4 + reg;
          if (r >= nRows) continue;
          outF[(size_t)r * D + col] = acc[i][j][reg] + bc;
        }
      }
    }
  }
}

extern "C" void kernel_launch(void* const* d_in, const int* in_sizes, int n_in,
                              void* d_out, int out_size, void* d_ws, size_t ws_size,
                              hipStream_t stream) {
  const float* feat = (const float*)d_in[0];
  const int* ei = (const int*)d_in[1];
  const float* Wl0 = (const float*)d_in[2];
  const float* Wr0 = (const float*)d_in[3];
  const float* b0 = (const float*)d_in[4];
  const float* Wl1 = (const float*)d_in[5];
  const float* Wr1 = (const float*)d_in[6];
  const float* b1 = (const float*)d_in[7];
  const float* Wl2 = (const float*)d_in[8];
  const float* Wr2 = (const float*)d_in[9];
  const float* b2 = (const float*)d_in[10];

  const int N = in_sizes[0] / D;   // 100000
  const int E = in_sizes[1] / 2;   // 1600000
  const int* src = ei;
  const int* dst = ei + E;

  // ---- workspace ----
  const size_t hfBytes = (size_t)N * D * 2;   // 25.6 MB
  char* wsp = (char*)d_ws;
  size_t off = 0;
  unsigned short* xhf   = (unsigned short*)(wsp + off); off += hfBytes;
  unsigned short* agghf = (unsigned short*)(wsp + off); off += hfBytes;
  unsigned short* Wt    = (unsigned short*)(wsp + off); off += ((size_t)3 * 128 * 256 * 2 + 511) & ~511ull;
  int* rowStart     = (int*)(wsp + off); off += ((size_t)(N + 1) * 4 + 511) & ~511ull;
  int* bucketTotal  = (int*)(wsp + off); off += 2048;
  int* buckOff      = (int*)(wsp + off); off += 2048;
  int* bucketCursor = (int*)(wsp + off); off += 2048;
  int* csrSrc    = (int*)(wsp + off); off += (size_t)E * 4;
  unsigned* pairs = (unsigned*)(wsp + off); off += (size_t)E * 4;  // 6.4 MB

  const int nBuck = (N + (1 << BSHIFT) - 1) >> BSHIFT;    // 196

  // ---- JAX partitionable threefry keys on host ----
  unsigned k1a, k1b, k2a, k2b;
  threefry2x32(0u, 42u, 0u, 0u, k1a, k1b);
  threefry2x32(0u, 42u, 0u, 1u, k2a, k2b);

  // ---- CSR build ----
  hipMemsetAsync(bucketTotal, 0, 1024, stream);
  bucket_count_kernel<<<(E + 4095) / 4096, 256, 0, stream>>>(dst, bucketTotal, E);
  scan_buckets_kernel<<<1, 256, 0, stream>>>(bucketTotal, buckOff, bucketCursor, nBuck);
  bucket_scatter_kernel<<<(E + 4095) / 4096, 256, 0, stream>>>(src, dst, bucketCursor, pairs, E, nBuck);
  local_fill_kernel<<<nBuck, 256, 0, stream>>>(pairs, buckOff, rowStart, csrSrc, N, nBuck);

  // ---- prep fp16 (slice-major) ----
  dim3 cvGrid((N * 2 + 255) / 256, 8);
  convert_feat_slice_kernel<<<cvGrid, 256, 0, stream>>>(feat, xhf, N);
  pack_weights_kernel<<<(3 * 128 * 256 + 255) / 256, 256, 0, stream>>>(
      Wl0, Wr0, Wl1, Wr1, Wl2, Wr2, Wt);

  dim3 blk(256);
  dim3 grdMax(((N + 15) / 16) * 8);
  dim3 grdGemm((N + TROWS - 1) / TROWS);
  float* outF = (float*)d_out;

  // ---- layer 0 ----
  gather_max_slice_kernel<<<grdMax, blk, 0, stream>>>((const uint4*)xhf, rowStart, csrSrc, (uint4*)agghf, N);
  fused_mfma_kernel<<<grdGemm, blk, 0, stream>>>(agghf, xhf, Wt, b0, outF, N, 0, k1a, k1b);

  // ---- layer 1 ----
  gather_max_slice_kernel<<<grdMax, blk, 0, stream>>>((const uint4*)xhf, rowStart, csrSrc, (uint4*)agghf, N);
  fused_mfma_kernel<<<grdGemm, blk, 0, stream>>>(agghf, xhf, Wt + 32768, b1, outF, N, 1, k2a, k2b);

  // ---- layer 2 (fp32 out) ----
  gather_max_slice_kernel<<<grdMax, blk, 0, stream>>>((const uint4*)xhf, rowStart, csrSrc, (uint4*)agghf, N);
  fused_mfma_kernel<<<grdGemm, blk, 0, stream>>>(agghf, xhf, Wt + 65536, b2, outF, N, 2, 0u, 0u);
}

// Round 6
// 509.557 us; speedup vs baseline: 1.2421x; 1.2421x over previous
//
#include <hip/hip_runtime.h>
#include <math.h>

#define D 128
#define BSHIFT 9              // bucket = 512 nodes
#define BCAP 12288            // LDS staging capacity (edges) per bucket

typedef __attribute__((ext_vector_type(8))) _Float16 half8;
typedef __attribute__((ext_vector_type(4))) float floatx4;
typedef __attribute__((ext_vector_type(4))) unsigned uintx4;

// ---------------- threefry2x32 (JAX-compatible, 20 rounds) ----------------
__host__ __device__ __forceinline__ unsigned rotl32(unsigned v, int r) {
  return (v << r) | (v >> (32 - r));
}

__host__ __device__ __forceinline__ void threefry2x32(unsigned k0, unsigned k1,
                                                      unsigned x0, unsigned x1,
                                                      unsigned &o0, unsigned &o1) {
  unsigned ks2 = k0 ^ k1 ^ 0x1BD11BDAu;
  unsigned v0 = x0 + k0;
  unsigned v1 = x1 + k1;
  v0 += v1; v1 = rotl32(v1, 13); v1 ^= v0;
  v0 += v1; v1 = rotl32(v1, 15); v1 ^= v0;
  v0 += v1; v1 = rotl32(v1, 26); v1 ^= v0;
  v0 += v1; v1 = rotl32(v1, 6);  v1 ^= v0;
  v0 += k1; v1 += ks2 + 1u;
  v0 += v1; v1 = rotl32(v1, 17); v1 ^= v0;
  v0 += v1; v1 = rotl32(v1, 29); v1 ^= v0;
  v0 += v1; v1 = rotl32(v1, 16); v1 ^= v0;
  v0 += v1; v1 = rotl32(v1, 24); v1 ^= v0;
  v0 += ks2; v1 += k0 + 2u;
  v0 += v1; v1 = rotl32(v1, 13); v1 ^= v0;
  v0 += v1; v1 = rotl32(v1, 15); v1 ^= v0;
  v0 += v1; v1 = rotl32(v1, 26); v1 ^= v0;
  v0 += v1; v1 = rotl32(v1, 6);  v1 ^= v0;
  v0 += k0; v1 += k1 + 3u;
  v0 += v1; v1 = rotl32(v1, 17); v1 ^= v0;
  v0 += v1; v1 = rotl32(v1, 29); v1 ^= v0;
  v0 += v1; v1 = rotl32(v1, 16); v1 ^= v0;
  v0 += v1; v1 = rotl32(v1, 24); v1 ^= v0;
  v0 += k1; v1 += ks2 + 4u;
  v0 += v1; v1 = rotl32(v1, 13); v1 ^= v0;
  v0 += v1; v1 = rotl32(v1, 15); v1 ^= v0;
  v0 += v1; v1 = rotl32(v1, 26); v1 ^= v0;
  v0 += v1; v1 = rotl32(v1, 6);  v1 ^= v0;
  v0 += ks2; v1 += k0 + 5u;
  o0 = v0; o1 = v1;
}

// float -> fp16 bits (RNE via v_cvt_f16_f32)
__device__ __forceinline__ unsigned short f2h(float f) {
  _Float16 h = (_Float16)f;
  return *(unsigned short*)&h;
}

// packed fp16 max (VOP3P, 1 instr for 2 elements)
__device__ __forceinline__ unsigned pkmax(unsigned a, unsigned b) {
  unsigned r;
  asm("v_pk_max_f16 %0, %1, %2" : "=v"(r) : "v"(a), "v"(b));
  return r;
}

// ================= CSR build (bucket-local, no global per-node atomics) ====

__global__ __launch_bounds__(256) void bucket_count_kernel(
    const int* __restrict__ dst, int* __restrict__ bucketTotal, int nEdges) {
  __shared__ int lc[256];
  int t = threadIdx.x;
  lc[t] = 0;
  __syncthreads();
  int e0 = blockIdx.x * 4096;
  for (int i = t; i < 4096; i += 256) {
    int e = e0 + i;
    if (e < nEdges) atomicAdd(&lc[dst[e] >> BSHIFT], 1);
  }
  __syncthreads();
  int c = lc[t];
  if (c > 0) atomicAdd(&bucketTotal[t], c);
}

__global__ __launch_bounds__(256) void scan_buckets_kernel(
    const int* __restrict__ bucketTotal, int* __restrict__ buckOff,
    int* __restrict__ bucketCursor, int nBuck) {
  __shared__ int s[256];
  int t = threadIdx.x;
  int v = (t < nBuck) ? bucketTotal[t] : 0;
  s[t] = v;
  __syncthreads();
  for (int off = 1; off < 256; off <<= 1) {
    int u = (t >= off) ? s[t - off] : 0;
    __syncthreads();
    s[t] += u;
    __syncthreads();
  }
  int excl = s[t] - v;
  if (t < nBuck) {
    buckOff[t] = excl;
    bucketCursor[t] = excl;
  } else if (t == nBuck) {
    buckOff[t] = s[255];  // total edge count
  }
}

// pairs entry packed: (src << 9) | (dst & 511)  — src < 2^17, fits 26 bits.
__global__ __launch_bounds__(256) void bucket_scatter_kernel(
    const int* __restrict__ src, const int* __restrict__ dst,
    int* __restrict__ bucketCursor, unsigned* __restrict__ pairs,
    int nEdges, int nBuck) {
  __shared__ int lcount[256];
  __shared__ int lbase[256];
  __shared__ int loff[256];
  int t = threadIdx.x;
  lcount[t] = 0; loff[t] = 0;
  __syncthreads();
  int e0 = blockIdx.x * 4096;
  for (int i = t; i < 4096; i += 256) {
    int e = e0 + i;
    if (e < nEdges) atomicAdd(&lcount[dst[e] >> BSHIFT], 1);
  }
  __syncthreads();
  if (t < nBuck) {
    int c = lcount[t];
    if (c > 0) lbase[t] = atomicAdd(&bucketCursor[t], c);
  }
  __syncthreads();
  for (int i = t; i < 4096; i += 256) {
    int e = e0 + i;
    if (e < nEdges) {
      int d = dst[e];
      int b = d >> BSHIFT;
      int lp = atomicAdd(&loff[b], 1);
      pairs[lbase[b] + lp] = ((unsigned)src[e] << BSHIFT) | ((unsigned)d & 511u);
    }
  }
}

// One block per bucket: count degrees in LDS, scan in LDS, emit rowStart,
// then single-writer place into csrSrc.
__global__ __launch_bounds__(256) void local_fill_kernel(
    const unsigned* __restrict__ pairs, const int* __restrict__ buckOff,
    int* __restrict__ rowStart, int* __restrict__ csrSrc,
    int nNodes, int nBuck) {
  __shared__ int sData[BCAP];           // 48 KB
  __shared__ int lcnt[1 << BSHIFT];     // 2 KB: counts, then running cursors
  __shared__ int sSum[256];             // 1 KB scan temp
  int b = blockIdx.x;
  int node0 = b << BSHIFT;
  int base = buckOff[b];
  int end = buckOff[b + 1];
  int cnt = end - base;
  int t = threadIdx.x;

  lcnt[t] = 0;
  lcnt[t + 256] = 0;
  __syncthreads();

  for (int i = base + t; i < end; i += 256)
    atomicAdd(&lcnt[pairs[i] & 511u], 1);
  __syncthreads();

  int c0 = lcnt[2 * t];
  int c1 = lcnt[2 * t + 1];
  int local = c0 + c1;
  sSum[t] = local;
  __syncthreads();
  for (int off = 1; off < 256; off <<= 1) {
    int v = (t >= off) ? sSum[t - off] : 0;
    __syncthreads();
    sSum[t] += v;
    __syncthreads();
  }
  int excl = sSum[t] - local;
  __syncthreads();
  lcnt[2 * t] = excl;
  lcnt[2 * t + 1] = excl + c0;
  int n0 = node0 + 2 * t;
  int n1 = n0 + 1;
  if (n0 < nNodes) rowStart[n0] = base + excl;
  if (n1 < nNodes) rowStart[n1] = base + excl + c0;
  if (b == nBuck - 1 && t == 255) rowStart[nNodes] = end;
  __syncthreads();

  if (cnt <= BCAP) {
    for (int i = base + t; i < end; i += 256) {
      unsigned p = pairs[i];
      int lp = atomicAdd(&lcnt[p & 511u], 1);
      sData[lp] = (int)(p >> BSHIFT);
    }
    __syncthreads();
    for (int i = t; i < cnt; i += 256)
      csrSrc[base + i] = sData[i];
  } else {
    for (int i = base + t; i < end; i += 256) {
      unsigned p = pairs[i];
      int lp = atomicAdd(&lcnt[p & 511u], 1);
      csrSrc[base + lp] = (int)(p >> BSHIFT);
    }
  }
}

// ========== prep: fp32 node-major -> fp16 SLICE-MAJOR [8][N][32B] ==========
__global__ __launch_bounds__(256) void convert_feat_slice_kernel(
    const float* __restrict__ f, unsigned short* __restrict__ o, int nN) {
  int s = blockIdx.y;
  int rem = blockIdx.x * 256 + threadIdx.x;   // [0, nN*2)
  if (rem >= nN * 2) return;
  int n = rem >> 1, h = rem & 1;
  const float* src = f + (size_t)n * D + s * 16 + h * 8;
  float4 v0 = *((const float4*)src);
  float4 v1 = *((const float4*)(src + 4));
  uint4 out;
  out.x = (unsigned)f2h(v0.x) | ((unsigned)f2h(v0.y) << 16);
  out.y = (unsigned)f2h(v0.z) | ((unsigned)f2h(v0.w) << 16);
  out.z = (unsigned)f2h(v1.x) | ((unsigned)f2h(v1.y) << 16);
  out.w = (unsigned)f2h(v1.z) | ((unsigned)f2h(v1.w) << 16);
  ((uint4*)o)[((size_t)s * nN + n) * 2 + h] = out;
}

// Wt[l][n][k] fp16, k<128 from Wl[k][n], k>=128 from Wr[k-128][n]
__global__ __launch_bounds__(256) void pack_weights_kernel(
    const float* __restrict__ Wl0, const float* __restrict__ Wr0,
    const float* __restrict__ Wl1, const float* __restrict__ Wr1,
    const float* __restrict__ Wl2, const float* __restrict__ Wr2,
    unsigned short* __restrict__ Wt) {
  int t = blockIdx.x * 256 + threadIdx.x;
  if (t >= 3 * 128 * 256) return;
  int l = t >> 15;
  int rem = t & 32767;
  int n = rem >> 8;
  int k = rem & 255;
  const float* Wl = (l == 0) ? Wl0 : (l == 1) ? Wl1 : Wl2;
  const float* Wr = (l == 0) ? Wr0 : (l == 1) ? Wr1 : Wr2;
  float v = (k < 128) ? Wl[k * D + n] : Wr[(k - 128) * D + n];
  Wt[t] = f2h(v);
}

// ============== gather segment-max, slice-major + XCD affinity ==============
// slice = blockIdx % 8 -> XCD s only touches feature slice s (3.2 MB, fits
// its 4 MB L2). Block = 64 nodes x 1 slice. Edge indices (contiguous csr
// range for the 64 nodes) staged once into LDS, so the per-edge chain is
// ds_read(idx) -> L2-hit granule load, unrolled x2 for MLP.
#define GN 64
#define GCAP 4096

__global__ __launch_bounds__(256) void gather_max_slice_kernel(
    const uint4* __restrict__ xs, const int* __restrict__ rowStart,
    const int* __restrict__ csrSrc, uint4* __restrict__ aggs, int nN) {
  __shared__ int sIdx[GCAP];    // 16 KB
  __shared__ int sRow[GN + 1];
  int b = blockIdx.x;
  int s = b & 7;
  int nb = b >> 3;
  int node0 = nb * GN;
  int tid = threadIdx.x;

  if (tid <= GN) {
    int nn = node0 + tid;
    if (nn > nN) nn = nN;
    sRow[tid] = rowStart[nn];
  }
  __syncthreads();
  int base = sRow[0];
  int cnt = sRow[GN] - base;
  bool useLds = (cnt <= GCAP);
  if (useLds) {
    for (int i = tid; i < cnt; i += 256) sIdx[i] = csrSrc[base + i];
  }
  __syncthreads();

  int wv = tid >> 6, lane = tid & 63;
  int nq = lane >> 4;            // node quarter [0,4)
  int slot = (lane & 15) >> 1;   // edge slot [0,8)
  int h = lane & 1;              // 16B half of the 32B granule
  size_t sbase = (size_t)s * nN;

  for (int r = wv * 4 + nq; r < GN; r += 16) {
    int n = node0 + r;
    if (n >= nN) break;          // uniform per 16-lane quarter
    int e0 = sRow[r] - base, e1 = sRow[r + 1] - base;
    unsigned m0 = 0xFC00FC00u, m1 = 0xFC00FC00u,  // packed fp16 -inf
             m2 = 0xFC00FC00u, m3 = 0xFC00FC00u;
    int e = e0 + slot;
    if (useLds) {
      for (; e + 8 < e1; e += 16) {          // 2 independent chains
        int ia = sIdx[e];
        int ib = sIdx[e + 8];
        uint4 va = xs[(sbase + (unsigned)ia) * 2 + h];
        uint4 vb = xs[(sbase + (unsigned)ib) * 2 + h];
        m0 = pkmax(m0, pkmax(va.x, vb.x));
        m1 = pkmax(m1, pkmax(va.y, vb.y));
        m2 = pkmax(m2, pkmax(va.z, vb.z));
        m3 = pkmax(m3, pkmax(va.w, vb.w));
      }
      if (e < e1) {
        int ia = sIdx[e];
        uint4 va = xs[(sbase + (unsigned)ia) * 2 + h];
        m0 = pkmax(m0, va.x); m1 = pkmax(m1, va.y);
        m2 = pkmax(m2, va.z); m3 = pkmax(m3, va.w);
      }
    } else {
      for (; e < e1; e += 8) {
        int ia = csrSrc[base + e];
        uint4 va = xs[(sbase + (unsigned)ia) * 2 + h];
        m0 = pkmax(m0, va.x); m1 = pkmax(m1, va.y);
        m2 = pkmax(m2, va.z); m3 = pkmax(m3, va.w);
      }
    }
    // reduce over the 8 edge slots (xor 2,4,8 within the 16-lane quarter)
    m0 = pkmax(m0, (unsigned)__shfl_xor((int)m0, 2, 64));
    m1 = pkmax(m1, (unsigned)__shfl_xor((int)m1, 2, 64));
    m2 = pkmax(m2, (unsigned)__shfl_xor((int)m2, 2, 64));
    m3 = pkmax(m3, (unsigned)__shfl_xor((int)m3, 2, 64));
    m0 = pkmax(m0, (unsigned)__shfl_xor((int)m0, 4, 64));
    m1 = pkmax(m1, (unsigned)__shfl_xor((int)m1, 4, 64));
    m2 = pkmax(m2, (unsigned)__shfl_xor((int)m2, 4, 64));
    m3 = pkmax(m3, (unsigned)__shfl_xor((int)m3, 4, 64));
    m0 = pkmax(m0, (unsigned)__shfl_xor((int)m0, 8, 64));
    m1 = pkmax(m1, (unsigned)__shfl_xor((int)m1, 8, 64));
    m2 = pkmax(m2, (unsigned)__shfl_xor((int)m2, 8, 64));
    m3 = pkmax(m3, (unsigned)__shfl_xor((int)m3, 8, 64));
    if ((lane & 15) < 2) {
      uintx4 rz = {0u, 0u, 0u, 0u};   // isolated node -> +0.0
      if (e0 != e1) { rz.x = m0; rz.y = m1; rz.z = m2; rz.w = m3; }
      __builtin_nontemporal_store(rz, (uintx4*)&aggs[(sbase + n) * 2 + h]);
    }
  }
}

// ====== MFMA layer: 64-row tile, slice-major in/out, coalesced stores ======
#define PA 280
#define TROWS 64

__global__ __launch_bounds__(256, 2) void fused_mfma_kernel(
    const unsigned short* __restrict__ agghf, unsigned short* __restrict__ xhf,
    const unsigned short* __restrict__ Wt, const float* __restrict__ bias,
    float* __restrict__ outF, int nRows, int mode, unsigned kk0, unsigned kk1) {
  __shared__ unsigned short sA[TROWS * PA];   // 35.8 KB

  const int tid = threadIdx.x;
  const int row0 = blockIdx.x * TROWS;
  const int wv = tid >> 6, lane = tid & 63;
  const int quad = lane >> 4, m16 = lane & 15;
  const int nbase = wv * 32;
  const int nN = nRows;
  const uint4* ag4 = (const uint4*)agghf;
  const uint4* xf4 = (const uint4*)xhf;

  // ---- stage A: 64 rows x 256 k from slice-major agg (k<128) + self ----
#pragma unroll
  for (int i = 0; i < 8; ++i) {
    int idx = i * 256 + tid;        // [0,2048)
    int part = idx >> 10;           // 0 = agg, 1 = self
    int rem = idx & 1023;
    int s = rem >> 7;
    int r = (rem >> 1) & 63;
    int h = rem & 1;
    uint4 v = make_uint4(0, 0, 0, 0);
    if (row0 + r < nRows) {
      const uint4* srcp = part ? xf4 : ag4;
      v = srcp[((size_t)s * nN + row0 + r) * 2 + h];
    }
    *((uint4*)(sA + r * PA + part * 128 + s * 16 + h * 8)) = v;
  }

  // ---- B fragments (L2-resident weights) ----
  half8 bfr[2][4][2];
#pragma unroll
  for (int kc = 0; kc < 2; ++kc)
#pragma unroll
    for (int ks = 0; ks < 4; ++ks)
#pragma unroll
      for (int j = 0; j < 2; ++j)
        bfr[kc][ks][j] = *((const half8*)(
            Wt + (size_t)(nbase + j * 16 + m16) * 256 + kc * 128 + ks * 32 + quad * 8));

  floatx4 acc[4][2];
#pragma unroll
  for (int i = 0; i < 4; ++i)
#pragma unroll
    for (int j = 0; j < 2; ++j) acc[i][j] = (floatx4)(0.0f);

  __syncthreads();

#pragma unroll
  for (int kc = 0; kc < 2; ++kc)
#pragma unroll
    for (int ks = 0; ks < 4; ++ks) {
      int kA = kc * 128 + ks * 32 + quad * 8;
#pragma unroll
      for (int i = 0; i < 4; ++i) {
        half8 a = *((const half8*)(sA + (m16 + 16 * i) * PA + kA));
        acc[i][0] = __builtin_amdgcn_mfma_f32_16x16x32_f16(a, bfr[kc][ks][0], acc[i][0], 0, 0, 0);
        acc[i][1] = __builtin_amdgcn_mfma_f32_16x16x32_f16(a, bfr[kc][ks][1], acc[i][1], 0, 0, 0);
      }
    }

  if (mode < 2) {
    // epilogue: ELU + dropout, stage fp16 tile in LDS, slice-major store
    __syncthreads();   // all MFMA reads of sA done before overwrite
#pragma unroll
    for (int j = 0; j < 2; ++j) {
      int col = nbase + j * 16 + m16;
      float bc = bias[col];
#pragma unroll
      for (int i = 0; i < 4; ++i) {
#pragma unroll
        for (int reg = 0; reg < 4; ++reg) {
          int r = i * 16 + quad * 4 + reg;
          if (row0 + r >= nRows) continue;
          float v = acc[i][j][reg] + bc;
          v = (v > 0.0f) ? v : (__expf(v) - 1.0f);   // ELU via hw exp
          unsigned jj = (unsigned)(row0 + r) * D + col;
          unsigned y0, y1;
          threefry2x32(kk0, kk1, 0u, jj, y0, y1);
          float u = __uint_as_float((((y0 ^ y1) >> 9)) | 0x3F800000u) - 1.0f;
          v = (u < 0.8f) ? v * 1.25f : 0.0f;
          sA[r * PA + col] = f2h(v);
        }
      }
    }
    __syncthreads();
    uint4* out4 = (uint4*)xhf;
#pragma unroll
    for (int i = 0; i < 4; ++i) {
      int idx = i * 256 + tid;      // [0,1024)
      int s = idx >> 7;
      int r = (idx >> 1) & 63;
      int h = idx & 1;
      if (row0 + r < nRows)
        out4[((size_t)s * nN + row0 + r) * 2 + h] =
            *((const uint4*)(sA + r * PA + s * 16 + h * 8));
    }
  } else {
    // final layer: fp32 out (node-major), 64 B-contiguous stores per quad
#pragma unroll
    for (int j = 0; j < 2; ++j) {
      int col = nbase + j * 16 + m16;
      float bc = bias[col];
#pragma unroll
      for (int i = 0; i < 4; ++i) {
#pragma unroll
        for (int reg = 0; reg < 4; ++reg) {
          int r = row0 + i * 16 + quad * 4 + reg;
          if (r >= nRows) continue;
          outF[(size_t)r * D + col] = acc[i][j][reg] + bc;
        }
      }
    }
  }
}

extern "C" void kernel_launch(void* const* d_in, const int* in_sizes, int n_in,
                              void* d_out, int out_size, void* d_ws, size_t ws_size,
                              hipStream_t stream) {
  const float* feat = (const float*)d_in[0];
  const int* ei = (const int*)d_in[1];
  const float* Wl0 = (const float*)d_in[2];
  const float* Wr0 = (const float*)d_in[3];
  const float* b0 = (const float*)d_in[4];
  const float* Wl1 = (const float*)d_in[5];
  const float* Wr1 = (const float*)d_in[6];
  const float* b1 = (const float*)d_in[7];
  const float* Wl2 = (const float*)d_in[8];
  const float* Wr2 = (const float*)d_in[9];
  const float* b2 = (const float*)d_in[10];

  const int N = in_sizes[0] / D;   // 100000
  const int E = in_sizes[1] / 2;   // 1600000
  const int* src = ei;
  const int* dst = ei + E;

  // ---- workspace ----
  const size_t hfBytes = (size_t)N * D * 2;   // 25.6 MB
  char* wsp = (char*)d_ws;
  size_t off = 0;
  unsigned short* xhf   = (unsigned short*)(wsp + off); off += hfBytes;
  unsigned short* agghf = (unsigned short*)(wsp + off); off += hfBytes;
  unsigned short* Wt    = (unsigned short*)(wsp + off); off += ((size_t)3 * 128 * 256 * 2 + 511) & ~511ull;
  int* rowStart     = (int*)(wsp + off); off += ((size_t)(N + 1) * 4 + 511) & ~511ull;
  int* bucketTotal  = (int*)(wsp + off); off += 2048;
  int* buckOff      = (int*)(wsp + off); off += 2048;
  int* bucketCursor = (int*)(wsp + off); off += 2048;
  int* csrSrc    = (int*)(wsp + off); off += (size_t)E * 4;
  unsigned* pairs = (unsigned*)(wsp + off); off += (size_t)E * 4;  // 6.4 MB

  const int nBuck = (N + (1 << BSHIFT) - 1) >> BSHIFT;    // 196

  // ---- JAX partitionable threefry keys on host ----
  unsigned k1a, k1b, k2a, k2b;
  threefry2x32(0u, 42u, 0u, 0u, k1a, k1b);
  threefry2x32(0u, 42u, 0u, 1u, k2a, k2b);

  // ---- CSR build ----
  hipMemsetAsync(bucketTotal, 0, 1024, stream);
  bucket_count_kernel<<<(E + 4095) / 4096, 256, 0, stream>>>(dst, bucketTotal, E);
  scan_buckets_kernel<<<1, 256, 0, stream>>>(bucketTotal, buckOff, bucketCursor, nBuck);
  bucket_scatter_kernel<<<(E + 4095) / 4096, 256, 0, stream>>>(src, dst, bucketCursor, pairs, E, nBuck);
  local_fill_kernel<<<nBuck, 256, 0, stream>>>(pairs, buckOff, rowStart, csrSrc, N, nBuck);

  // ---- prep fp16 (slice-major) ----
  dim3 cvGrid((N * 2 + 255) / 256, 8);
  convert_feat_slice_kernel<<<cvGrid, 256, 0, stream>>>(feat, xhf, N);
  pack_weights_kernel<<<(3 * 128 * 256 + 255) / 256, 256, 0, stream>>>(
      Wl0, Wr0, Wl1, Wr1, Wl2, Wr2, Wt);

  dim3 blk(256);
  dim3 grdMax(((N + GN - 1) / GN) * 8);
  dim3 grdGemm((N + TROWS - 1) / TROWS);
  float* outF = (float*)d_out;

  // ---- layer 0 ----
  gather_max_slice_kernel<<<grdMax, blk, 0, stream>>>((const uint4*)xhf, rowStart, csrSrc, (uint4*)agghf, N);
  fused_mfma_kernel<<<grdGemm, blk, 0, stream>>>(agghf, xhf, Wt, b0, outF, N, 0, k1a, k1b);

  // ---- layer 1 ----
  gather_max_slice_kernel<<<grdMax, blk, 0, stream>>>((const uint4*)xhf, rowStart, csrSrc, (uint4*)agghf, N);
  fused_mfma_kernel<<<grdGemm, blk, 0, stream>>>(agghf, xhf, Wt + 32768, b1, outF, N, 1, k2a, k2b);

  // ---- layer 2 (fp32 out) ----
  gather_max_slice_kernel<<<grdMax, blk, 0, stream>>>((const uint4*)xhf, rowStart, csrSrc, (uint4*)agghf, N);
  fused_mfma_kernel<<<grdGemm, blk, 0, stream>>>(agghf, xhf, Wt + 65536, b2, outF, N, 2, 0u, 0u);
}

// Round 8
// 479.992 us; speedup vs baseline: 1.3186x; 1.0616x over previous
//
#include <hip/hip_runtime.h>
#include <math.h>

#define D 128
#define BSHIFT 9              // bucket = 512 nodes
#define BCAP 12288            // LDS staging capacity (edges) per bucket

typedef __attribute__((ext_vector_type(8))) _Float16 half8;
typedef __attribute__((ext_vector_type(4))) float floatx4;

// ---------------- threefry2x32 (JAX-compatible, 20 rounds) ----------------
__host__ __device__ __forceinline__ unsigned rotl32(unsigned v, int r) {
  return (v << r) | (v >> (32 - r));
}

__host__ __device__ __forceinline__ void threefry2x32(unsigned k0, unsigned k1,
                                                      unsigned x0, unsigned x1,
                                                      unsigned &o0, unsigned &o1) {
  unsigned ks2 = k0 ^ k1 ^ 0x1BD11BDAu;
  unsigned v0 = x0 + k0;
  unsigned v1 = x1 + k1;
  v0 += v1; v1 = rotl32(v1, 13); v1 ^= v0;
  v0 += v1; v1 = rotl32(v1, 15); v1 ^= v0;
  v0 += v1; v1 = rotl32(v1, 26); v1 ^= v0;
  v0 += v1; v1 = rotl32(v1, 6);  v1 ^= v0;
  v0 += k1; v1 += ks2 + 1u;
  v0 += v1; v1 = rotl32(v1, 17); v1 ^= v0;
  v0 += v1; v1 = rotl32(v1, 29); v1 ^= v0;
  v0 += v1; v1 = rotl32(v1, 16); v1 ^= v0;
  v0 += v1; v1 = rotl32(v1, 24); v1 ^= v0;
  v0 += ks2; v1 += k0 + 2u;
  v0 += v1; v1 = rotl32(v1, 13); v1 ^= v0;
  v0 += v1; v1 = rotl32(v1, 15); v1 ^= v0;
  v0 += v1; v1 = rotl32(v1, 26); v1 ^= v0;
  v0 += v1; v1 = rotl32(v1, 6);  v1 ^= v0;
  v0 += k0; v1 += k1 + 3u;
  v0 += v1; v1 = rotl32(v1, 17); v1 ^= v0;
  v0 += v1; v1 = rotl32(v1, 29); v1 ^= v0;
  v0 += v1; v1 = rotl32(v1, 16); v1 ^= v0;
  v0 += v1; v1 = rotl32(v1, 24); v1 ^= v0;
  v0 += k1; v1 += ks2 + 4u;
  v0 += v1; v1 = rotl32(v1, 13); v1 ^= v0;
  v0 += v1; v1 = rotl32(v1, 15); v1 ^= v0;
  v0 += v1; v1 = rotl32(v1, 26); v1 ^= v0;
  v0 += v1; v1 = rotl32(v1, 6);  v1 ^= v0;
  v0 += ks2; v1 += k0 + 5u;
  o0 = v0; o1 = v1;
}

// float -> fp16 bits (RNE via v_cvt_f16_f32)
__device__ __forceinline__ unsigned short f2h(float f) {
  _Float16 h = (_Float16)f;
  return *(unsigned short*)&h;
}

// packed fp16 max (VOP3P, 1 instr for 2 elements)
__device__ __forceinline__ unsigned pkmax(unsigned a, unsigned b) {
  unsigned r;
  asm("v_pk_max_f16 %0, %1, %2" : "=v"(r) : "v"(a), "v"(b));
  return r;
}

// ================= CSR build (bucket-local, no global per-node atomics) ====

__global__ __launch_bounds__(256) void bucket_count_kernel(
    const int* __restrict__ dst, int* __restrict__ bucketTotal, int nEdges) {
  __shared__ int lc[256];
  int t = threadIdx.x;
  lc[t] = 0;
  __syncthreads();
  int e0 = blockIdx.x * 4096;
  for (int i = t; i < 4096; i += 256) {
    int e = e0 + i;
    if (e < nEdges) atomicAdd(&lc[dst[e] >> BSHIFT], 1);
  }
  __syncthreads();
  int c = lc[t];
  if (c > 0) atomicAdd(&bucketTotal[t], c);
}

__global__ __launch_bounds__(256) void scan_buckets_kernel(
    const int* __restrict__ bucketTotal, int* __restrict__ buckOff,
    int* __restrict__ bucketCursor, int nBuck) {
  __shared__ int s[256];
  int t = threadIdx.x;
  int v = (t < nBuck) ? bucketTotal[t] : 0;
  s[t] = v;
  __syncthreads();
  for (int off = 1; off < 256; off <<= 1) {
    int u = (t >= off) ? s[t - off] : 0;
    __syncthreads();
    s[t] += u;
    __syncthreads();
  }
  int excl = s[t] - v;
  if (t < nBuck) {
    buckOff[t] = excl;
    bucketCursor[t] = excl;
  } else if (t == nBuck) {
    buckOff[t] = s[255];  // total edge count
  }
}

// pairs entry packed: (src << 9) | (dst & 511)  — src < 2^17, fits 26 bits.
__global__ __launch_bounds__(256) void bucket_scatter_kernel(
    const int* __restrict__ src, const int* __restrict__ dst,
    int* __restrict__ bucketCursor, unsigned* __restrict__ pairs,
    int nEdges, int nBuck) {
  __shared__ int lcount[256];
  __shared__ int lbase[256];
  __shared__ int loff[256];
  int t = threadIdx.x;
  lcount[t] = 0; loff[t] = 0;
  __syncthreads();
  int e0 = blockIdx.x * 4096;
  for (int i = t; i < 4096; i += 256) {
    int e = e0 + i;
    if (e < nEdges) atomicAdd(&lcount[dst[e] >> BSHIFT], 1);
  }
  __syncthreads();
  if (t < nBuck) {
    int c = lcount[t];
    if (c > 0) lbase[t] = atomicAdd(&bucketCursor[t], c);
  }
  __syncthreads();
  for (int i = t; i < 4096; i += 256) {
    int e = e0 + i;
    if (e < nEdges) {
      int d = dst[e];
      int b = d >> BSHIFT;
      int lp = atomicAdd(&loff[b], 1);
      pairs[lbase[b] + lp] = ((unsigned)src[e] << BSHIFT) | ((unsigned)d & 511u);
    }
  }
}

// One block per bucket: count degrees in LDS, scan in LDS, emit rowStart,
// then single-writer place into csrSrc.
__global__ __launch_bounds__(256) void local_fill_kernel(
    const unsigned* __restrict__ pairs, const int* __restrict__ buckOff,
    int* __restrict__ rowStart, int* __restrict__ csrSrc,
    int nNodes, int nBuck) {
  __shared__ int sData[BCAP];           // 48 KB
  __shared__ int lcnt[1 << BSHIFT];     // 2 KB: counts, then running cursors
  __shared__ int sSum[256];             // 1 KB scan temp
  int b = blockIdx.x;
  int node0 = b << BSHIFT;
  int base = buckOff[b];
  int end = buckOff[b + 1];
  int cnt = end - base;
  int t = threadIdx.x;

  lcnt[t] = 0;
  lcnt[t + 256] = 0;
  __syncthreads();

  for (int i = base + t; i < end; i += 256)
    atomicAdd(&lcnt[pairs[i] & 511u], 1);
  __syncthreads();

  int c0 = lcnt[2 * t];
  int c1 = lcnt[2 * t + 1];
  int local = c0 + c1;
  sSum[t] = local;
  __syncthreads();
  for (int off = 1; off < 256; off <<= 1) {
    int v = (t >= off) ? sSum[t - off] : 0;
    __syncthreads();
    sSum[t] += v;
    __syncthreads();
  }
  int excl = sSum[t] - local;
  __syncthreads();
  lcnt[2 * t] = excl;
  lcnt[2 * t + 1] = excl + c0;
  int n0 = node0 + 2 * t;
  int n1 = n0 + 1;
  if (n0 < nNodes) rowStart[n0] = base + excl;
  if (n1 < nNodes) rowStart[n1] = base + excl + c0;
  if (b == nBuck - 1 && t == 255) rowStart[nNodes] = end;
  __syncthreads();

  if (cnt <= BCAP) {
    for (int i = base + t; i < end; i += 256) {
      unsigned p = pairs[i];
      int lp = atomicAdd(&lcnt[p & 511u], 1);
      sData[lp] = (int)(p >> BSHIFT);
    }
    __syncthreads();
    for (int i = t; i < cnt; i += 256)
      csrSrc[base + i] = sData[i];
  } else {
    for (int i = base + t; i < end; i += 256) {
      unsigned p = pairs[i];
      int lp = atomicAdd(&lcnt[p & 511u], 1);
      csrSrc[base + lp] = (int)(p >> BSHIFT);
    }
  }
}

// ================= prep: fp32 -> fp16 (node-major) =================
__global__ __launch_bounds__(256) void convert_feat_kernel(
    const float* __restrict__ f, unsigned short* __restrict__ o, int nElems) {
  int i = (blockIdx.x * 256 + threadIdx.x) * 4;
  if (i + 3 < nElems) {
    float4 v = *((const float4*)(f + i));
    unsigned a = (unsigned)f2h(v.x) | ((unsigned)f2h(v.y) << 16);
    unsigned b = (unsigned)f2h(v.z) | ((unsigned)f2h(v.w) << 16);
    *((uint2*)(o + i)) = make_uint2(a, b);
  } else {
    for (int j = i; j < nElems; ++j) o[j] = f2h(f[j]);
  }
}

// Wt[l][n][k] fp16, k<128 from Wl[k][n], k>=128 from Wr[k-128][n]
__global__ __launch_bounds__(256) void pack_weights_kernel(
    const float* __restrict__ Wl0, const float* __restrict__ Wr0,
    const float* __restrict__ Wl1, const float* __restrict__ Wr1,
    const float* __restrict__ Wl2, const float* __restrict__ Wr2,
    unsigned short* __restrict__ Wt) {
  int t = blockIdx.x * 256 + threadIdx.x;
  if (t >= 3 * 128 * 256) return;
  int l = t >> 15;
  int rem = t & 32767;
  int n = rem >> 8;
  int k = rem & 255;
  const float* Wl = (l == 0) ? Wl0 : (l == 1) ? Wl1 : Wl2;
  const float* Wr = (l == 0) ? Wr0 : (l == 1) ? Wr1 : Wr2;
  float v = (k < 128) ? Wl[k * D + n] : Wr[(k - 128) * D + n];
  Wt[t] = f2h(v);
}

// ================= gather segment-max on fp16 rows (node-major) ===========
// One wave per node (max TLP; latency-bound phase). 16 B/lane: 16 lanes
// cover the 256 B row; four 16-lane quarters take different edges.
// Unrolled to 16 edges/iter = 4 independent idx+granule chains per lane
// (R3 had 2) to hide the ~600-900 cy L3-served latency.
__global__ __launch_bounds__(256) void gather_max_f16_kernel(
    const uint4* __restrict__ x8, const int* __restrict__ rowStart,
    const int* __restrict__ csrSrc, uint4* __restrict__ agg8, int nNodes) {
  int n = blockIdx.x * 4 + (threadIdx.x >> 6);
  if (n >= nNodes) return;
  int lane = threadIdx.x & 63;
  int q = lane >> 4;        // quarter: which edge of a group of 4
  int l16 = lane & 15;      // 16-byte segment within the row
  int e0 = rowStart[n], e1 = rowStart[n + 1];
  unsigned m0 = 0xFC00FC00u, m1 = 0xFC00FC00u,  // packed fp16 -inf
           m2 = 0xFC00FC00u, m3 = 0xFC00FC00u;
  int e = e0;
  for (; e + 15 < e1; e += 16) {    // 4 independent chains
    int sa = csrSrc[e + q];
    int sb = csrSrc[e + 4 + q];
    int sc = csrSrc[e + 8 + q];
    int sd = csrSrc[e + 12 + q];
    uint4 va = x8[(size_t)sa * 16 + l16];
    uint4 vb = x8[(size_t)sb * 16 + l16];
    uint4 vc = x8[(size_t)sc * 16 + l16];
    uint4 vd = x8[(size_t)sd * 16 + l16];
    m0 = pkmax(m0, pkmax(pkmax(va.x, vb.x), pkmax(vc.x, vd.x)));
    m1 = pkmax(m1, pkmax(pkmax(va.y, vb.y), pkmax(vc.y, vd.y)));
    m2 = pkmax(m2, pkmax(pkmax(va.z, vb.z), pkmax(vc.z, vd.z)));
    m3 = pkmax(m3, pkmax(pkmax(va.w, vb.w), pkmax(vc.w, vd.w)));
  }
  if (e + 7 < e1) {                 // 2 chains
    int sa = csrSrc[e + q];
    int sb = csrSrc[e + 4 + q];
    uint4 va = x8[(size_t)sa * 16 + l16];
    uint4 vb = x8[(size_t)sb * 16 + l16];
    m0 = pkmax(m0, pkmax(va.x, vb.x));
    m1 = pkmax(m1, pkmax(va.y, vb.y));
    m2 = pkmax(m2, pkmax(va.z, vb.z));
    m3 = pkmax(m3, pkmax(va.w, vb.w));
    e += 8;
  }
  if (e + 3 < e1) {
    int sa = csrSrc[e + q];
    uint4 va = x8[(size_t)sa * 16 + l16];
    m0 = pkmax(m0, va.x); m1 = pkmax(m1, va.y);
    m2 = pkmax(m2, va.z); m3 = pkmax(m3, va.w);
    e += 4;
  }
  for (; e < e1; ++e) {     // <4 leftover: all quarters read same row
    int sa = csrSrc[e];
    uint4 va = x8[(size_t)sa * 16 + l16];
    m0 = pkmax(m0, va.x); m1 = pkmax(m1, va.y);
    m2 = pkmax(m2, va.z); m3 = pkmax(m3, va.w);
  }
  // combine the four quarters (packed shuffles)
  m0 = pkmax(m0, (unsigned)__shfl_xor((int)m0, 16, 64));
  m1 = pkmax(m1, (unsigned)__shfl_xor((int)m1, 16, 64));
  m2 = pkmax(m2, (unsigned)__shfl_xor((int)m2, 16, 64));
  m3 = pkmax(m3, (unsigned)__shfl_xor((int)m3, 16, 64));
  m0 = pkmax(m0, (unsigned)__shfl_xor((int)m0, 32, 64));
  m1 = pkmax(m1, (unsigned)__shfl_xor((int)m1, 32, 64));
  m2 = pkmax(m2, (unsigned)__shfl_xor((int)m2, 32, 64));
  m3 = pkmax(m3, (unsigned)__shfl_xor((int)m3, 32, 64));
  uint4 r = make_uint4(0u, 0u, 0u, 0u);  // isolated node -> +0.0
  if (e0 != e1) r = make_uint4(m0, m1, m2, m3);
  if (q == 0) agg8[(size_t)n * 16 + l16] = r;
}

// ====== MFMA layer: 64-row tile, LDS-staged coalesced fp16 stores ======
#define PA 280
#define TROWS 64

__global__ __launch_bounds__(256, 2) void fused_mfma_kernel(
    const unsigned short* __restrict__ agghf, unsigned short* __restrict__ xhf,
    const unsigned short* __restrict__ Wt, const float* __restrict__ bias,
    float* __restrict__ outF, int nRows, int mode, unsigned kk0, unsigned kk1) {
  __shared__ unsigned short sA[TROWS * PA];   // 35.8 KB

  const int tid = threadIdx.x;
  const int row0 = blockIdx.x * TROWS;
  const int wv = tid >> 6, lane = tid & 63;
  const int quad = lane >> 4, m16 = lane & 15;
  const int nbase = wv * 32;

  // ---- stage A: 64 rows x 256 k (agg cols 0..127, self cols 128..255) ----
#pragma unroll
  for (int i = 0; i < 8; ++i) {
    int idx = i * 256 + tid;
    int r = idx >> 5;
    int seg = idx & 31;
    uint4 v = make_uint4(0, 0, 0, 0);
    if (row0 + r < nRows) {
      if (seg < 16) v = ((const uint4*)(agghf + (size_t)(row0 + r) * D))[seg];
      else          v = ((const uint4*)(xhf  + (size_t)(row0 + r) * D))[seg - 16];
    }
    *((uint4*)(sA + r * PA + seg * 8)) = v;
  }

  // ---- B fragments (L2-resident weights) ----
  half8 bfr[2][4][2];
#pragma unroll
  for (int kc = 0; kc < 2; ++kc)
#pragma unroll
    for (int ks = 0; ks < 4; ++ks)
#pragma unroll
      for (int j = 0; j < 2; ++j)
        bfr[kc][ks][j] = *((const half8*)(
            Wt + (size_t)(nbase + j * 16 + m16) * 256 + kc * 128 + ks * 32 + quad * 8));

  floatx4 acc[4][2];
#pragma unroll
  for (int i = 0; i < 4; ++i)
#pragma unroll
    for (int j = 0; j < 2; ++j) acc[i][j] = (floatx4)(0.0f);

  __syncthreads();

#pragma unroll
  for (int kc = 0; kc < 2; ++kc)
#pragma unroll
    for (int ks = 0; ks < 4; ++ks) {
      int kA = kc * 128 + ks * 32 + quad * 8;
#pragma unroll
      for (int i = 0; i < 4; ++i) {
        half8 a = *((const half8*)(sA + (m16 + 16 * i) * PA + kA));
        acc[i][0] = __builtin_amdgcn_mfma_f32_16x16x32_f16(a, bfr[kc][ks][0], acc[i][0], 0, 0, 0);
        acc[i][1] = __builtin_amdgcn_mfma_f32_16x16x32_f16(a, bfr[kc][ks][1], acc[i][1], 0, 0, 0);
      }
    }

  if (mode < 2) {
    // epilogue: ELU + dropout, stage fp16 tile in LDS, coalesced store
    __syncthreads();   // all MFMA reads of sA done before overwrite
#pragma unroll
    for (int j = 0; j < 2; ++j) {
      int col = nbase + j * 16 + m16;
      float bc = bias[col];
#pragma unroll
      for (int i = 0; i < 4; ++i) {
#pragma unroll
        for (int reg = 0; reg < 4; ++reg) {
          int r = i * 16 + quad * 4 + reg;
          if (row0 + r >= nRows) continue;
          float v = acc[i][j][reg] + bc;
          v = (v > 0.0f) ? v : (__expf(v) - 1.0f);   // ELU via hw exp
          unsigned jj = (unsigned)(row0 + r) * D + col;
          unsigned y0, y1;
          threefry2x32(kk0, kk1, 0u, jj, y0, y1);
          float u = __uint_as_float((((y0 ^ y1) >> 9)) | 0x3F800000u) - 1.0f;
          v = (u < 0.8f) ? v * 1.25f : 0.0f;
          sA[r * PA + col] = f2h(v);
        }
      }
    }
    __syncthreads();
#pragma unroll
    for (int i = 0; i < 4; ++i) {
      int idx = i * 256 + tid;
      int r = idx >> 4;
      int seg = idx & 15;
      if (row0 + r < nRows)
        ((uint4*)xhf)[(size_t)(row0 + r) * 16 + seg] =
            *((const uint4*)(sA + r * PA + seg * 8));
    }
  } else {
    // final layer: fp32 out, 64 B-contiguous stores per quad
#pragma unroll
    for (int j = 0; j < 2; ++j) {
      int col = nbase + j * 16 + m16;
      float bc = bias[col];
#pragma unroll
      for (int i = 0; i < 4; ++i) {
#pragma unroll
        for (int reg = 0; reg < 4; ++reg) {
          int r = row0 + i * 16 + quad * 4 + reg;
          if (r >= nRows) continue;
          outF[(size_t)r * D + col] = acc[i][j][reg] + bc;
        }
      }
    }
  }
}

extern "C" void kernel_launch(void* const* d_in, const int* in_sizes, int n_in,
                              void* d_out, int out_size, void* d_ws, size_t ws_size,
                              hipStream_t stream) {
  const float* feat = (const float*)d_in[0];
  const int* ei = (const int*)d_in[1];
  const float* Wl0 = (const float*)d_in[2];
  const float* Wr0 = (const float*)d_in[3];
  const float* b0 = (const float*)d_in[4];
  const float* Wl1 = (const float*)d_in[5];
  const float* Wr1 = (const float*)d_in[6];
  const float* b1 = (const float*)d_in[7];
  const float* Wl2 = (const float*)d_in[8];
  const float* Wr2 = (const float*)d_in[9];
  const float* b2 = (const float*)d_in[10];

  const int N = in_sizes[0] / D;   // 100000
  const int E = in_sizes[1] / 2;   // 1600000
  const int* src = ei;
  const int* dst = ei + E;

  // ---- workspace ----
  const size_t hfBytes = (size_t)N * D * 2;   // 25.6 MB
  char* wsp = (char*)d_ws;
  size_t off = 0;
  unsigned short* xhf   = (unsigned short*)(wsp + off); off += hfBytes;
  unsigned short* agghf = (unsigned short*)(wsp + off); off += hfBytes;
  unsigned short* Wt    = (unsigned short*)(wsp + off); off += ((size_t)3 * 128 * 256 * 2 + 511) & ~511ull;
  int* rowStart     = (int*)(wsp + off); off += ((size_t)(N + 1) * 4 + 511) & ~511ull;
  int* bucketTotal  = (int*)(wsp + off); off += 2048;
  int* buckOff      = (int*)(wsp + off); off += 2048;
  int* bucketCursor = (int*)(wsp + off); off += 2048;
  int* csrSrc    = (int*)(wsp + off); off += (size_t)E * 4;
  unsigned* pairs = (unsigned*)(wsp + off); off += (size_t)E * 4;  // 6.4 MB

  const int nBuck = (N + (1 << BSHIFT) - 1) >> BSHIFT;    // 196

  // ---- JAX partitionable threefry keys on host ----
  unsigned k1a, k1b, k2a, k2b;
  threefry2x32(0u, 42u, 0u, 0u, k1a, k1b);
  threefry2x32(0u, 42u, 0u, 1u, k2a, k2b);

  // ---- CSR build ----
  hipMemsetAsync(bucketTotal, 0, 1024, stream);
  bucket_count_kernel<<<(E + 4095) / 4096, 256, 0, stream>>>(dst, bucketTotal, E);
  scan_buckets_kernel<<<1, 256, 0, stream>>>(bucketTotal, buckOff, bucketCursor, nBuck);
  bucket_scatter_kernel<<<(E + 4095) / 4096, 256, 0, stream>>>(src, dst, bucketCursor, pairs, E, nBuck);
  local_fill_kernel<<<nBuck, 256, 0, stream>>>(pairs, buckOff, rowStart, csrSrc, N, nBuck);

  // ---- prep fp16 ----
  convert_feat_kernel<<<(N * D / 4 + 255) / 256, 256, 0, stream>>>(feat, xhf, N * D);
  pack_weights_kernel<<<(3 * 128 * 256 + 255) / 256, 256, 0, stream>>>(
      Wl0, Wr0, Wl1, Wr1, Wl2, Wr2, Wt);

  dim3 blk(256);
  dim3 grdMax((N + 3) / 4);
  dim3 grdGemm((N + TROWS - 1) / TROWS);
  float* outF = (float*)d_out;

  // ---- layer 0 ----
  gather_max_f16_kernel<<<grdMax, blk, 0, stream>>>((const uint4*)xhf, rowStart, csrSrc, (uint4*)agghf, N);
  fused_mfma_kernel<<<grdGemm, blk, 0, stream>>>(agghf, xhf, Wt, b0, outF, N, 0, k1a, k1b);

  // ---- layer 1 ----
  gather_max_f16_kernel<<<grdMax, blk, 0, stream>>>((const uint4*)xhf, rowStart, csrSrc, (uint4*)agghf, N);
  fused_mfma_kernel<<<grdGemm, blk, 0, stream>>>(agghf, xhf, Wt + 32768, b1, outF, N, 1, k2a, k2b);

  // ---- layer 2 (fp32 out) ----
  gather_max_f16_kernel<<<grdMax, blk, 0, stream>>>((const uint4*)xhf, rowStart, csrSrc, (uint4*)agghf, N);
  fused_mfma_kernel<<<grdGemm, blk, 0, stream>>>(agghf, xhf, Wt + 65536, b2, outF, N, 2, 0u, 0u);
}